// Round 8
// baseline (142.497 us; speedup 1.0000x reference)
//
#include <hip/hip_runtime.h>

// Problem constants (from setup_inputs)
#define B_     2
#define NQ     16384     // B*N
#define M2     8192
#define M3     4096
#define M4     2048
#define NBIN   64
#define GDOT_BLOCKS 7168
#define SCAT_K_BLOCKS 112   // 32+32+16+16+8+8
#define SCAT_Q_BLOCKS 64    // 32+32
#define K2_BLOCKS (GDOT_BLOCKS + SCAT_K_BLOCKS + SCAT_Q_BLOCKS)

// Referee model (jax/XLA, verified R4): d = (su - 2*p) + sk, left-to-right fp32.
// su/sk: elementwise square + sequential reduce, NO FMA.
// p: K=3 GEMM ascending-k FMA chain. fl(2p) exact -> fmaf(-2,p,su) form ok.
__device__ __forceinline__ float np_sqnorm(float x, float y, float z) {
    return __fadd_rn(__fadd_rn(__fmul_rn(x, x), __fmul_rn(y, y)), __fmul_rn(z, z));
}
__device__ __forceinline__ float ref_dist(float su, float ux, float uy, float uz,
                                          float kx, float ky, float kz, float sk) {
    float p = fmaf(uz, kz, fmaf(uy, ky, __fmul_rn(ux, kx)));
    return __fadd_rn(fmaf(-2.0f, p, su), sk);
}
__device__ __forceinline__ int zbin(float z) {
    int b = (int)(z * 64.0f);
    return min(63, max(0, b));
}
__device__ __forceinline__ int wave_min_i(int v) {
    for (int o = 32; o; o >>= 1) v = min(v, __shfl_xor(v, o, 64));
    return v;
}
__device__ __forceinline__ int wave_max_i(int v) {
    for (int o = 32; o; o >>= 1) v = max(v, __shfl_xor(v, o, 64));
    return v;
}

// ---------------------------------------------------------------- kernel 1
// wc fold (blocks 0-1) + per-group z-hist + prefix (blocks 2-9).
// Groups: 0,1=lvl2 b0,b1  2,3=lvl3  4,5=lvl4  6,7=queries b0,b1.
__global__ void k_setup_v8(const float* __restrict__ w_fc, const float* __restrict__ w_cls,
                           const float* __restrict__ pts,
                           const float* __restrict__ xyz2, const float* __restrict__ xyz3,
                           const float* __restrict__ xyz4,
                           float* __restrict__ wc, int* __restrict__ bs,
                           int* __restrict__ cur) {
    int bx = blockIdx.x, tid = threadIdx.x;
    if (bx < 2) {
        int c = bx * 256 + tid;
        if (c < 320) {
            float acc = 0.f;
#pragma unroll
            for (int j = 0; j < 64; ++j) acc = fmaf(w_fc[c * 64 + j], w_cls[j], acc);
            wc[c] = acc;
        }
        return;
    }
    int g = bx - 2;
    const float* src; int M;
    if (g < 2)      { src = xyz2 + g * M2 * 3;       M = M2; }
    else if (g < 4) { src = xyz3 + (g - 2) * M3 * 3; M = M3; }
    else if (g < 6) { src = xyz4 + (g - 4) * M4 * 3; M = M4; }
    else            { src = pts  + (g - 6) * 8192 * 3; M = 8192; }
    __shared__ int h[NBIN];
    if (tid < NBIN) h[tid] = 0;
    __syncthreads();
    for (int j = tid; j < M; j += 256) atomicAdd(&h[zbin(src[j * 3 + 2])], 1);
    __syncthreads();
    if (tid == 0) {
        int run = 0;
        for (int b = 0; b < NBIN; ++b) { bs[g * 65 + b] = run; run += h[b]; }
        bs[g * 65 + 64] = run;
    }
    __syncthreads();
    if (tid < NBIN) cur[g * 64 + tid] = bs[g * 65 + tid];
}

// ---------------------------------------------------------------- kernel 2
// gdot (one wave per known point) + z-binned scatter of known pts & queries.
__global__ void k_build_v8(const float* __restrict__ pts,
                           const float* __restrict__ xyz2, const float* __restrict__ xyz3,
                           const float* __restrict__ xyz4,
                           const float* __restrict__ f2, const float* __restrict__ f3,
                           const float* __restrict__ f4, const float* __restrict__ wc,
                           float* __restrict__ g2, float* __restrict__ g3,
                           float* __restrict__ g4,
                           float4* __restrict__ pk, int* __restrict__ oi,
                           float4* __restrict__ uq, int* __restrict__ qmap,
                           int* __restrict__ cur) {
    int bx = blockIdx.x, tid = threadIdx.x;
    if (bx < GDOT_BLOCKS) {
        int gid  = bx * 256 + tid;
        int w    = gid >> 6;
        int lane = gid & 63;
        float v;
        if (w < 16384) {
            v = f2[(size_t)w * 64 + lane] * wc[lane];
        } else if (w < 24576) {
            size_t base = (size_t)(w - 16384) * 128;
            v = fmaf(f3[base + 64 + lane], wc[128 + lane], f3[base + lane] * wc[64 + lane]);
        } else {
            size_t base = (size_t)(w - 24576) * 128;
            v = fmaf(f4[base + 64 + lane], wc[256 + lane], f4[base + lane] * wc[192 + lane]);
        }
        for (int off = 32; off; off >>= 1) v += __shfl_down(v, off, 64);
        if (lane == 0) {
            if (w < 16384) g2[w] = v;
            else if (w < 24576) g3[w - 16384] = v;
            else g4[w - 24576] = v;
        }
        return;
    }
    bx -= GDOT_BLOCKS;
    __shared__ int cnt[NBIN], base[NBIN];
    if (tid < NBIN) cnt[tid] = 0;
    __syncthreads();
    if (bx < SCAT_K_BLOCKS) {
        int g, j0;
        if (bx < 32)       { g = 0; j0 = bx * 256; }
        else if (bx < 64)  { g = 1; j0 = (bx - 32) * 256; }
        else if (bx < 80)  { g = 2; j0 = (bx - 64) * 256; }
        else if (bx < 96)  { g = 3; j0 = (bx - 80) * 256; }
        else if (bx < 104) { g = 4; j0 = (bx - 96) * 256; }
        else               { g = 5; j0 = (bx - 104) * 256; }
        const float* src = (g < 2) ? xyz2 + g * M2 * 3
                         : (g < 4) ? xyz3 + (g - 2) * M3 * 3
                                   : xyz4 + (g - 4) * M4 * 3;
        int gb = (g < 2) ? g * M2 : (g < 4) ? 16384 + (g - 2) * M3 : 24576 + (g - 4) * M4;
        int j = j0 + tid;
        float x = src[j * 3], y = src[j * 3 + 1], z = src[j * 3 + 2];
        int bin = zbin(z);
        int off = atomicAdd(&cnt[bin], 1);
        __syncthreads();
        if (tid < NBIN) base[tid] = atomicAdd(&cur[g * 64 + tid], cnt[tid]);
        __syncthreads();
        int slot = gb + base[bin] + off;
        pk[slot] = make_float4(x, y, z, np_sqnorm(x, y, z));
        oi[slot] = j;                          // orig index within (level,batch)
        return;
    }
    bx -= SCAT_K_BLOCKS;
    {   // query scatter
        int b = bx >> 5;
        int j = (bx & 31) * 256 + tid;         // [0,8192) within batch
        const float* src = pts + (size_t)b * 8192 * 3;
        float x = src[j * 3], y = src[j * 3 + 1], z = src[j * 3 + 2];
        int bin = zbin(z);
        int g = 6 + b;
        int off = atomicAdd(&cnt[bin], 1);
        __syncthreads();
        if (tid < NBIN) base[tid] = atomicAdd(&cur[g * 64 + tid], cnt[tid]);
        __syncthreads();
        int slot = b * 8192 + base[bin] + off;
        uq[slot]   = make_float4(x, y, z, np_sqnorm(x, y, z));
        qmap[slot] = b * 8192 + j;             // orig global query index
    }
}

// ---------------------------------------------------------------- kernel 3
// Windowed scan + merge. Block = qtile (64 z-sorted queries), 12 waves =
// 3 levels x 4 chunks. Prologue: own-bin values-only top3 -> T (certified
// >= referee d3). Window: bins covering z +- sqrt(T+1e-5) (exact pruning,
// margin >> fp32 expansion rounding). Gated insert, (d, orig_idx) lex.
#define STEP_A(KV)                                                          \
    {                                                                       \
        float d_ = ref_dist(suq, ux, uy, uz, KV.x, KV.y, KV.z, KV.w);       \
        float m1_ = __builtin_amdgcn_fmed3f(d_, a0, a1);                    \
        float m2_ = __builtin_amdgcn_fmed3f(d_, a1, a2);                    \
        a0 = fminf(d_, a0); a1 = m1_; a2 = m2_;                             \
    }

#define LEX_INS(D, O)                                                       \
    {                                                                       \
        bool l2_ = ((D) < e2) || ((D) == e2 && (O) < j2v);                  \
        bool l1_ = ((D) < e1) || ((D) == e1 && (O) < j1v);                  \
        bool l0_ = ((D) < e0) || ((D) == e0 && (O) < j0v);                  \
        j2v = l1_ ? j1v : (l2_ ? (O) : j2v);  e2 = l1_ ? e1 : (l2_ ? (D) : e2); \
        j1v = l0_ ? j0v : (l1_ ? (O) : j1v);  e1 = l0_ ? e0 : (l1_ ? (D) : e1); \
        j0v = l0_ ? (O) : j0v;                e0 = l0_ ? (D) : e0;          \
    }

#define STEP_B(KV, O)                                                       \
    {                                                                       \
        float db_ = ref_dist(suq, ux, uy, uz, KV.x, KV.y, KV.z, KV.w);      \
        if (__any(db_ <= e2)) { int ob_ = (O); LEX_INS(db_, ob_); }         \
    }

__launch_bounds__(768)
__global__ void k_scan_v8(const float4* __restrict__ pk, const int* __restrict__ oi,
                          const float4* __restrict__ uq, const int* __restrict__ qmap,
                          const int* __restrict__ bs,
                          const float* __restrict__ g2, const float* __restrict__ g3,
                          const float* __restrict__ g4,
                          float* __restrict__ out) {
    __shared__ float ld[12][3][64];
    __shared__ int   li[12][3][64];
    int qtile = blockIdx.x;
    int b     = qtile >> 7;
    int w     = threadIdx.x >> 6;     // 0..11
    int lane  = threadIdx.x & 63;
    int lvl   = w >> 2;               // 0..2
    int c4    = w & 3;                // chunk 0..3

    float4 u = uq[(qtile << 6) + lane];
    float ux = u.x, uy = u.y, uz = u.z, suq = u.w;

    int gb = (lvl == 0) ? b * M2 : (lvl == 1) ? 16384 + b * M3 : 24576 + b * M4;
    const int* bsg = bs + (lvl * 2 + b) * 65;
    const float4* pkg = pk + gb;
    const int*    oig = oi + gb;

    // ---- prologue: own-bin range, values-only top3 (quarter per wave)
    int bq  = zbin(uz);
    int blo = __builtin_amdgcn_readfirstlane(wave_min_i(bq));
    int bhi = __builtin_amdgcn_readfirstlane(wave_max_i(bq));
    int S0 = bsg[blo], E0 = bsg[bhi + 1];
    int L0 = E0 - S0;
    int pa = __builtin_amdgcn_readfirstlane(S0 + ((L0 * c4) >> 2));
    int pe = __builtin_amdgcn_readfirstlane(S0 + ((L0 * (c4 + 1)) >> 2));

    float a0 = 3e38f, a1 = 3e38f, a2 = 3e38f;
    int t = pa;
    for (; t + 4 <= pe; t += 4) {
        float4 k0 = pkg[t], k1 = pkg[t + 1], k2 = pkg[t + 2], k3 = pkg[t + 3];
        STEP_A(k0); STEP_A(k1); STEP_A(k2); STEP_A(k3);
    }
    for (; t < pe; ++t) { float4 kv = pkg[t]; STEP_A(kv); }
    ld[w][0][lane] = a0; ld[w][1][lane] = a1; ld[w][2][lane] = a2;
    __syncthreads();

    // ---- T = 3rd-min across this level's 4 wave-triples
    float t0 = 3e38f, t1 = 3e38f, t2 = 3e38f;
#pragma unroll
    for (int j = 0; j < 4; ++j)
#pragma unroll
        for (int k = 0; k < 3; ++k) {
            float v = ld[lvl * 4 + j][k][lane];
            float m1 = __builtin_amdgcn_fmed3f(v, t0, t1);
            float m2 = __builtin_amdgcn_fmed3f(v, t1, t2);
            t0 = fminf(v, t0); t1 = m1; t2 = m2;
        }
    float T = t2;
    __syncthreads();   // LDS reuse barrier

    // ---- window scan (quarter per wave), slots init to Tp = nextafter(T)
    float s = sqrtf(T + 1e-5f);
    int bl = min(63, max(0, (int)((uz - s) * 64.0f)));
    int bh = min(63, max(0, (int)((uz + s) * 64.0f)));
    int BL = __builtin_amdgcn_readfirstlane(wave_min_i(bl));
    int BH = __builtin_amdgcn_readfirstlane(wave_max_i(bh));
    int S = bsg[BL], E = bsg[BH + 1];
    int L = E - S;
    int wa = __builtin_amdgcn_readfirstlane(S + ((L * c4) >> 2));
    int we = __builtin_amdgcn_readfirstlane(S + ((L * (c4 + 1)) >> 2));

    int tbits = __float_as_int(T);
    float Tp = (T > 0.f) ? __int_as_float(tbits + 1)
             : (T < 0.f) ? __int_as_float(tbits - 1) : 1e-45f;
    float e0 = Tp, e1 = Tp, e2 = Tp;
    int j0v = 0x7fffffff, j1v = 0x7fffffff, j2v = 0x7fffffff;

    t = wa;
    for (; t + 4 <= we; t += 4) {
        float4 k0 = pkg[t], k1 = pkg[t + 1], k2 = pkg[t + 2], k3 = pkg[t + 3];
        int o0 = oig[t], o1 = oig[t + 1], o2 = oig[t + 2], o3 = oig[t + 3];
        STEP_B(k0, o0); STEP_B(k1, o1); STEP_B(k2, o2); STEP_B(k3, o3);
    }
    for (; t < we; ++t) { float4 kv = pkg[t]; STEP_B(kv, oig[t]); }
    ld[w][0][lane] = e0; ld[w][1][lane] = e1; ld[w][2][lane] = e2;
    li[w][0][lane] = j0v; li[w][1][lane] = j1v; li[w][2][lane] = j2v;
    __syncthreads();

    // ---- final merge by wave 0: fold 12 triples/level, weights, g-gather
    if (w == 0) {
        int qo = qmap[(qtile << 6) + lane];
        double acc = 0.0;
        for (int Lv = 0; Lv < 3; ++Lv) {
            float e0 = 3e38f, e1 = 3e38f, e2 = 3e38f;
            int j0v = 0x7fffffff, j1v = 0x7fffffff, j2v = 0x7fffffff;
#pragma unroll
            for (int j = 0; j < 4; ++j)
#pragma unroll
                for (int k = 0; k < 3; ++k) {
                    float d = ld[Lv * 4 + j][k][lane];
                    int   o = li[Lv * 4 + j][k][lane];
                    LEX_INS(d, o);
                }
            const float* gl = (Lv == 0) ? g2 + b * M2
                            : (Lv == 1) ? g3 + b * M3 : g4 + b * M4;
            // referee weights, bit-exact fp32: r=1/(d+1e-8); w=r/((r0+r1)+r2)
            float r0 = __fdiv_rn(1.0f, __fadd_rn(e0, 1e-8f));
            float r1 = __fdiv_rn(1.0f, __fadd_rn(e1, 1e-8f));
            float r2 = __fdiv_rn(1.0f, __fadd_rn(e2, 1e-8f));
            float sw = __fadd_rn(__fadd_rn(r0, r1), r2);
            float w0 = __fdiv_rn(r0, sw), w1 = __fdiv_rn(r1, sw), w2 = __fdiv_rn(r2, sw);
            acc += (double)w0 * (double)gl[j0v] + (double)w1 * (double)gl[j1v]
                 + (double)w2 * (double)gl[j2v];
        }
        out[qo] = (float)acc;
    }
}

// ---------------------------------------------------------------- launch
extern "C" void kernel_launch(void* const* d_in, const int* in_sizes, int n_in,
                              void* d_out, int out_size, void* d_ws, size_t ws_size,
                              hipStream_t stream) {
    const float* pts   = (const float*)d_in[0];
    const float* xyz2  = (const float*)d_in[1];
    const float* feat2 = (const float*)d_in[2];
    const float* xyz3  = (const float*)d_in[3];
    const float* feat3 = (const float*)d_in[4];
    const float* xyz4  = (const float*)d_in[5];
    const float* feat4 = (const float*)d_in[6];
    const float* w_fc  = (const float*)d_in[7];
    const float* w_cls = (const float*)d_in[8];
    float* out = (float*)d_out;

    // workspace layout (~1.02 MB)
    float4* pk   = (float4*)d_ws;          // 28672 float4 (16B aligned)
    float4* uq   = pk + 28672;             // 16384 float4
    float*  g2   = (float*)(uq + 16384);   // 16384
    float*  g3   = g2 + 16384;             // 8192
    float*  g4   = g3 + 8192;              // 4096
    float*  wc   = g4 + 4096;              // 320
    int*    oi   = (int*)(wc + 320);       // 28672
    int*    qmap = oi + 28672;             // 16384
    int*    bs   = qmap + 16384;           // 8*65
    int*    cur  = bs + 520;               // 8*64

    k_setup_v8<<<10, 256, 0, stream>>>(w_fc, w_cls, pts, xyz2, xyz3, xyz4, wc, bs, cur);
    k_build_v8<<<K2_BLOCKS, 256, 0, stream>>>(pts, xyz2, xyz3, xyz4,
                                              feat2, feat3, feat4, wc,
                                              g2, g3, g4, pk, oi, uq, qmap, cur);
    k_scan_v8<<<256, 768, 0, stream>>>(pk, oi, uq, qmap, bs, g2, g3, g4, out);
}